// Round 4
// baseline (762.002 us; speedup 1.0000x reference)
//
#include <hip/hip_runtime.h>
#include <stdint.h>

#define N_B 32
#define C_D 256
#define T_D 1024

typedef unsigned short u16;
typedef __attribute__((ext_vector_type(8))) short short8;
typedef __attribute__((ext_vector_type(4))) float f32x4;

__device__ __forceinline__ u16 f2bf(float f) {
    unsigned x = __float_as_uint(f);
    return (u16)((x + 0x7fffu + ((x >> 16) & 1u)) >> 16);  // RNE
}

__device__ __forceinline__ void gld16(const void* g, void* l) {
    __builtin_amdgcn_global_load_lds(
        (const __attribute__((address_space(1))) uint32_t*)g,
        (__attribute__((address_space(3))) uint32_t*)l, 16, 0, 0);
}

// ------- convert+transpose: X fp32 (n,c,t) -> XT bf16 (n,t,c), 64x64 tiles -------
__global__ __launch_bounds__(256) void ct_f2b(const float* __restrict__ X,
                                              u16* __restrict__ XT) {
    __shared__ u16 lds[64][65];
    const int n  = blockIdx.z;
    const int t0 = blockIdx.x * 64;
    const int c0 = blockIdx.y * 64;
    const float* Xn = X + (size_t)n * (C_D * T_D);
    u16* XTn = XT + (size_t)n * (T_D * C_D);
    const int tid = threadIdx.x;
    const int row = tid >> 2;        // 0..63 (c within tile)
    const int tq  = (tid & 3) * 16;  // t-base within tile
    const float* src = Xn + (size_t)(c0 + row) * T_D + t0 + tq;
#pragma unroll
    for (int i = 0; i < 4; ++i) {
        float4 v = *(const float4*)(src + i * 4);
        lds[row][tq + i * 4 + 0] = f2bf(v.x);
        lds[row][tq + i * 4 + 1] = f2bf(v.y);
        lds[row][tq + i * 4 + 2] = f2bf(v.z);
        lds[row][tq + i * 4 + 3] = f2bf(v.w);
    }
    __syncthreads();
    const int r  = tid >> 3;
    const int c8 = (tid & 7) * 8;
#pragma unroll
    for (int p = 0; p < 2; ++p) {
        const int tt = r + p * 32;  // t within tile
        union { u16 u[8]; uint4 v; } o;
#pragma unroll
        for (int j = 0; j < 8; ++j) o.u[j] = lds[c8 + j][tt];
        *(uint4*)(XTn + (size_t)(t0 + tt) * C_D + c0 + c8) = o.v;
    }
}

// ---------------- convert fp32 -> bf16, flat ----------------
__global__ __launch_bounds__(256) void conv_f2b(const float* __restrict__ in,
                                                u16* __restrict__ out, int n) {
    int i = blockIdx.x * 256 + threadIdx.x;
    if (i < n) out[i] = f2bf(in[i]);
}

// --------- GEMM: Out[m,n] = epi(scale * sum_k A[m,k]*B[n,k] (+bias)) -------
// A,B bf16 (rows K-contig). Out fp32 if F32OUT else bf16.
// EPI: 0 = scale only; 1 = tanh(x + bias[n]); 2 = tanh(x + bias[m])
template <int EPI, bool F32OUT>
__global__ __launch_bounds__(256) void gemm_abt(
        const u16* __restrict__ A, const u16* __restrict__ B,
        const float* __restrict__ bias, void* __restrict__ OutV,
        int Kdim, int ldo, long sA, long sB, long sO, float scale)
{
    __shared__ __align__(16) u16 smA[128 * 32];
    __shared__ __align__(16) u16 smB[128 * 32];

    const int nb = blockIdx.z;
    const int n0 = blockIdx.x * 128;
    const int m0 = blockIdx.y * 128;
    const int tid = threadIdx.x;

    const u16* Ab = A + (size_t)nb * sA;
    const u16* Bb = B + (size_t)nb * sB;

    const int srow = tid >> 2;
    const int sk8  = (tid & 3) * 8;
    const u16* gA0 = Ab + (size_t)(m0 + srow) * Kdim + sk8;
    const u16* gA1 = gA0 + (size_t)64 * Kdim;
    const u16* gB0 = Bb + (size_t)(n0 + srow) * Kdim + sk8;
    const u16* gB1 = gB0 + (size_t)64 * Kdim;
    u16* lA0 = smA + tid * 8;
    u16* lA1 = smA + 2048 + tid * 8;
    u16* lB0 = smB + tid * 8;
    u16* lB1 = smB + 2048 + tid * 8;

    const int lane = tid & 63;
    const int w    = tid >> 6;
    const int wm   = (w >> 1) * 64;
    const int wn   = (w & 1) * 64;
    const int l15  = lane & 15;
    const int quad = lane >> 4;

    f32x4 acc[4][4];
#pragma unroll
    for (int i = 0; i < 4; ++i)
#pragma unroll
        for (int j = 0; j < 4; ++j) acc[i][j] = (f32x4){0.f, 0.f, 0.f, 0.f};

    for (int kb = 0; kb < Kdim; kb += 32) {
        gld16(gA0 + kb, lA0);
        gld16(gA1 + kb, lA1);
        gld16(gB0 + kb, lB0);
        gld16(gB1 + kb, lB1);
        __syncthreads();
        short8 af[4], bfr[4];
#pragma unroll
        for (int i = 0; i < 4; ++i) {
            af[i]  = *(const short8*)(smA + (wm + i * 16 + l15) * 32 + quad * 8);
            bfr[i] = *(const short8*)(smB + (wn + i * 16 + l15) * 32 + quad * 8);
        }
#pragma unroll
        for (int mi = 0; mi < 4; ++mi)
#pragma unroll
            for (int ni = 0; ni < 4; ++ni)
                acc[mi][ni] = __builtin_amdgcn_mfma_f32_16x16x32_bf16(
                        af[mi], bfr[ni], acc[mi][ni], 0, 0, 0);
        __syncthreads();
    }

#pragma unroll
    for (int mi = 0; mi < 4; ++mi) {
        const int mb = m0 + wm + mi * 16 + quad * 4;
#pragma unroll
        for (int r = 0; r < 4; ++r) {
            const int m = mb + r;
            float bm = 0.f;
            if (EPI == 2) bm = bias[m];
#pragma unroll
            for (int ni = 0; ni < 4; ++ni) {
                const int nn = n0 + wn + ni * 16 + l15;
                float v = acc[mi][ni][r] * scale;
                if (EPI == 1) v = tanhf(v + bias[nn]);
                if (EPI == 2) v = tanhf(v + bm);
                if (F32OUT)
                    ((float*)OutV)[(size_t)nb * sO + (size_t)m * ldo + nn] = v;
                else
                    ((u16*)OutV)[(size_t)nb * sO + (size_t)m * ldo + nn] = f2bf(v);
            }
        }
    }
}

// ---- softmax over s (strided) of fp32 A(n,s,t), in place; coalesced in t ----
__global__ __launch_bounds__(256) void softmax_cols(float* __restrict__ S) {
    const int n = blockIdx.y;
    const int t = blockIdx.x * 256 + threadIdx.x;
    float* A = S + (size_t)n * T_D * T_D + t;

    float m = -1e30f, l = 0.f;
    for (int s = 0; s < T_D; ++s) {
        float x = A[(size_t)s * T_D];
        if (x > m) { l = l * __expf(m - x) + 1.f; m = x; }
        else       { l += __expf(x - m); }
    }
    const float rL = 1.0f / l;
    for (int s = 0; s < T_D; ++s) {
        float x = A[(size_t)s * T_D];
        A[(size_t)s * T_D] = __expf(x - m) * rL;
    }
}

// ----- R GEMM: R(c,t) = sum_s Vp(c,s) * A(s,t);  Vp bf16, A fp32, R fp32 -----
// B-tile staged via LDS transpose (fp32 -> bf16).
__global__ __launch_bounds__(256) void gemm_r(
        const u16* __restrict__ Vp, const float* __restrict__ S,
        float* __restrict__ R)
{
    __shared__ __align__(16) u16 smA[128 * 32];
    __shared__ __align__(16) u16 smB[128 * 32];

    const int nb = blockIdx.z;
    const int n0 = blockIdx.x * 128;   // t
    const int m0 = blockIdx.y * 128;   // c
    const int tid = threadIdx.x;

    const u16* Ab = Vp + (size_t)nb * (C_D * T_D);
    const float* Sb = S + (size_t)nb * T_D * T_D;
    float* Rb = R + (size_t)nb * (C_D * T_D);

    const int srow = tid >> 2;
    const int sk8  = (tid & 3) * 8;
    const u16* gA0 = Ab + (size_t)(m0 + srow) * T_D + sk8;
    const u16* gA1 = gA0 + (size_t)64 * T_D;
    u16* lA0 = smA + tid * 8;
    u16* lA1 = smA + 2048 + tid * 8;

    // B transpose-staging map: sr = s-row in tile (0..31), tq*16 = t-base
    const int sr = tid >> 3;
    const int tq = (tid & 7) * 16;

    const int lane = tid & 63;
    const int w    = tid >> 6;
    const int wm   = (w >> 1) * 64;
    const int wn   = (w & 1) * 64;
    const int l15  = lane & 15;
    const int quad = lane >> 4;

    f32x4 acc[4][4];
#pragma unroll
    for (int i = 0; i < 4; ++i)
#pragma unroll
        for (int j = 0; j < 4; ++j) acc[i][j] = (f32x4){0.f, 0.f, 0.f, 0.f};

    for (int kb = 0; kb < T_D; kb += 32) {
        gld16(gA0 + kb, lA0);
        gld16(gA1 + kb, lA1);
        const float* srcB = Sb + (size_t)(kb + sr) * T_D + n0 + tq;
#pragma unroll
        for (int i = 0; i < 4; ++i) {
            float4 v = *(const float4*)(srcB + i * 4);
            smB[(tq + i * 4 + 0) * 32 + sr] = f2bf(v.x);
            smB[(tq + i * 4 + 1) * 32 + sr] = f2bf(v.y);
            smB[(tq + i * 4 + 2) * 32 + sr] = f2bf(v.z);
            smB[(tq + i * 4 + 3) * 32 + sr] = f2bf(v.w);
        }
        __syncthreads();
        short8 af[4], bfr[4];
#pragma unroll
        for (int i = 0; i < 4; ++i) {
            af[i]  = *(const short8*)(smA + (wm + i * 16 + l15) * 32 + quad * 8);
            bfr[i] = *(const short8*)(smB + (wn + i * 16 + l15) * 32 + quad * 8);
        }
#pragma unroll
        for (int mi = 0; mi < 4; ++mi)
#pragma unroll
            for (int ni = 0; ni < 4; ++ni)
                acc[mi][ni] = __builtin_amdgcn_mfma_f32_16x16x32_bf16(
                        af[mi], bfr[ni], acc[mi][ni], 0, 0, 0);
        __syncthreads();
    }

#pragma unroll
    for (int mi = 0; mi < 4; ++mi) {
        const int mb = m0 + wm + mi * 16 + quad * 4;
#pragma unroll
        for (int r = 0; r < 4; ++r) {
            const int m = mb + r;
#pragma unroll
            for (int ni = 0; ni < 4; ++ni) {
                const int nn = n0 + wn + ni * 16 + l15;
                Rb[(size_t)m * T_D + nn] = acc[mi][ni][r];
            }
        }
    }
}

extern "C" void kernel_launch(void* const* d_in, const int* in_sizes, int n_in,
                              void* d_out, int out_size, void* d_ws, size_t ws_size,
                              hipStream_t stream) {
    const float* Qf = (const float*)d_in[0];
    const float* Kf = (const float*)d_in[1];
    const float* Vf = (const float*)d_in[2];
    const float* Wq = (const float*)d_in[3];
    const float* bq = (const float*)d_in[4];
    const float* Wk = (const float*)d_in[5];
    const float* bk = (const float*)d_in[6];
    const float* Wv = (const float*)d_in[7];
    const float* bv = (const float*)d_in[8];

    float* Rout = (float*)d_out;                       // (n,c,t) fp32, 33.5 MB
    float* Aout = Rout + (size_t)N_B * C_D * T_D;      // (n,s,t) fp32, 134 MB

    // phase-1 scratch (all dead before their regions are overwritten):
    u16* QT  = (u16*)Rout;                 // bf16 (n,t,c), 16MB, in R region
    u16* KT  = (u16*)Rout + 8388608;       // bf16 (n,s,c), 16MB, in R region
    u16* VT  = (u16*)Aout;                 // bf16 (n,s,c), 16MB, in A region
    u16* Wqb = (u16*)Aout + 8388608;       // bf16 weights after VT
    u16* Wkb = Wqb + 65536;
    u16* Wvb = Wkb + 65536;
    // projections overwrite the consumed fp32 input buffers
    u16* QpT = (u16*)d_in[0];              // bf16 (n,t,c)
    u16* KpT = (u16*)d_in[1];              // bf16 (n,s,c)
    u16* Vp  = (u16*)d_in[2];              // bf16 (n,c,s)

    dim3 blk(256);
    const long sX = (long)T_D * C_D;   // 262144 elements
    const long sS = (long)T_D * T_D;   // 1048576 elements

    // 1) convert+transpose inputs fp32 -> bf16
    ct_f2b<<<dim3(16, 4, N_B), blk, 0, stream>>>(Qf, QT);
    ct_f2b<<<dim3(16, 4, N_B), blk, 0, stream>>>(Kf, KT);
    ct_f2b<<<dim3(16, 4, N_B), blk, 0, stream>>>(Vf, VT);
    // 2) convert weights
    conv_f2b<<<dim3(256), blk, 0, stream>>>(Wq, Wqb, 65536);
    conv_f2b<<<dim3(256), blk, 0, stream>>>(Wk, Wkb, 65536);
    conv_f2b<<<dim3(256), blk, 0, stream>>>(Wv, Wvb, 65536);

    // 3) projections (bf16 out into consumed input buffers)
    gemm_abt<1, false><<<dim3(2, 8, N_B), blk, 0, stream>>>(QT, Wqb, bq, QpT, C_D, C_D, sX, 0, sX, 1.0f);
    gemm_abt<1, false><<<dim3(2, 8, N_B), blk, 0, stream>>>(KT, Wkb, bk, KpT, C_D, C_D, sX, 0, sX, 1.0f);
    gemm_abt<2, false><<<dim3(8, 2, N_B), blk, 0, stream>>>(Wvb, VT, bv, Vp, C_D, T_D, 0, sX, sX, 1.0f);

    // 4) scores: S(s,t) = KpT(s,c) . QpT(t,c)^T / 16 -> fp32 straight into A output
    //    (overwrites VT + converted weights, both dead)
    gemm_abt<0, true><<<dim3(8, 8, N_B), blk, 0, stream>>>(KpT, QpT, nullptr, Aout, C_D, T_D, sX, sX, sS, 0.0625f);

    // 5) softmax over s (strided), in place, fp32
    softmax_cols<<<dim3(4, N_B), blk, 0, stream>>>(Aout);

    // 6) R(c,t) = Vp(c,s) . A(s,t) -> fp32 (overwrites dead QT/KT)
    gemm_r<<<dim3(8, 2, N_B), blk, 0, stream>>>(Vp, Aout, Rout);
}